// Round 8
// baseline (131.790 us; speedup 1.0000x reference)
//
#include <hip/hip_runtime.h>
#include <hip/hip_bf16.h>

#define BATCH 32
#define WW 900
#define CCH 256
#define KHALF 128     // K columns per block (K-split x2)
#define MSTRIP 128    // M rows per block
#define NCHUNK 32     // B rows per chunk
#define NCHUNKS 29    // 29*32 = 928 >= 900

typedef __bf16 bf16x8 __attribute__((ext_vector_type(8)));
typedef __bf16 bf16x4 __attribute__((ext_vector_type(4)));
typedef float f32x4 __attribute__((ext_vector_type(4)));

// ws layout (floats): inv12 [0, 8192) = [32][256]; sums [16384, 16384+segs*64*256)
#define INV_OFF 0
#define SUMS_OFF 16384

// ---------------- norm pass 1: partial sums of squares ----------------
__global__ void nc_norm_partial(const float* __restrict__ x1,
                                const float* __restrict__ x2,
                                float* __restrict__ sums,
                                int segs, int rowsper) {
    int blk = blockIdx.x;
    int seg = blk % segs;
    int b = (blk / segs) & 31;
    int which = blk / (segs * 32);
    const float* x = which ? x2 : x1;
    int c = threadIdx.x;
    int r0 = seg * rowsper;
    int r1 = r0 + rowsper;
    if (r1 > WW) r1 = WW;
    const float* p = x + ((size_t)b * WW + r0) * CCH + c;
    float s = 0.f;
    #pragma unroll 4
    for (int w = 0; w < r1 - r0; ++w) {
        float v = p[(size_t)w * CCH];
        s = fmaf(v, v, s);
    }
    sums[(((size_t)(which * 32 + b)) * segs + seg) * CCH + c] = s;
}

// ---------------- norm pass 2: inv12 = rsqrt(s1)*rsqrt(s2) per (b, c) ----------------
__global__ void nc_norm_finalize(float* __restrict__ ws, int segs) {
    int i = blockIdx.x * 256 + threadIdx.x;   // 32*256 outputs
    int c = i & 255;
    int b = i >> 8;
    const float* s1 = ws + SUMS_OFF + (size_t)b * segs * CCH + c;
    const float* s2 = ws + SUMS_OFF + (size_t)(32 + b) * segs * CCH + c;
    float t1 = 0.f, t2 = 0.f;
    for (int q = 0; q < segs; ++q) { t1 += s1[(size_t)q * CCH]; t2 += s2[(size_t)q * CCH]; }
    ws[INV_OFF + i] = rsqrtf(fmaxf(t1, 1e-12f)) * rsqrtf(fmaxf(t2, 1e-12f));
}

// ---------------- main: barrier-free GEMM + diagonal reduction ----------------
// grid = 512: b = blockIdx&31 (XCD-local per batch), strip = (blockIdx>>5)&7, kh = blockIdx>>8.
// A' = x1 * inv1*inv2 staged once -> register fragments. B = RAW x2 read straight from
// global (L2) into registers each chunk, converted fp32->bf16 in-reg. No __syncthreads
// in the main loop: epilogue scratch is wave-private, partial[] via LDS atomics.
__global__ __launch_bounds__(256, 2)
void nc_corr(const float* __restrict__ x1,
             const float* __restrict__ x2,
             const float* __restrict__ ws,
             float* __restrict__ out) {
    __shared__ __bf16 Abuf[MSTRIP * KHALF];       // 32 KB (dead after frag load)
    __shared__ float scratch[4][16][65];          // 16.25 KB, wave-private rows
    __shared__ float partial[WW];                 // 3.6 KB

    const int tid = threadIdx.x;
    const int b = blockIdx.x & 31;
    const int strip = (blockIdx.x >> 5) & 7;
    const int kh = blockIdx.x >> 8;
    const int m0 = strip * MSTRIP;
    const int k0 = kh * KHALF;

    const float* __restrict__ inv12 = ws + INV_OFF + b * CCH + k0;
    const float* __restrict__ x1b = x1 + (size_t)b * WW * CCH + k0;
    const float* __restrict__ x2b = x2 + (size_t)b * WW * CCH + k0;

    for (int i = tid; i < WW; i += 256) partial[i] = 0.f;
    for (int i = tid; i < 4 * 16 * 65; i += 256) ((float*)scratch)[i] = 0.f;

    const int lane = tid & 63;
    const int wave = tid >> 6;     // m-slice: rows m0 + wave*32 .. +31
    const int fr = lane & 15;
    const int fq = lane >> 4;
    const int sr = tid >> 5;       // staging row base 0..7
    const int sg = tid & 31;       // staging float4 col 0..31

    // ---- Stage A' once: coalesced, x1 * inv12, bf16, swizzled ----
    {
        float4 iv = *(const float4*)(inv12 + sg * 4);
        #pragma unroll
        for (int k = 0; k < 16; ++k) {
            const int row = sr + 8 * k;        // 0..127
            const int m = m0 + row;
            float4 f = make_float4(0.f, 0.f, 0.f, 0.f);
            if (m < WW) f = *(const float4*)(x1b + (size_t)m * CCH + sg * 4);
            bf16x4 v = { (__bf16)(f.x * iv.x), (__bf16)(f.y * iv.y),
                         (__bf16)(f.z * iv.z), (__bf16)(f.w * iv.w) };
            *(bf16x4*)(&Abuf[row * KHALF + (((sg >> 1) ^ (row & 7)) << 3) + (sg & 1) * 4]) = v;
        }
    }
    __syncthreads();   // A staged; scratch+partial zeroed (only barrier before the end)

    // ---- A fragments: LDS -> registers once, pinned ----
    bf16x8 af[2][4];
    #pragma unroll
    for (int mt = 0; mt < 2; ++mt)
        #pragma unroll
        for (int kk = 0; kk < 4; ++kk) {
            const int row = wave * 32 + mt * 16 + fr;
            const int g = (kk * 4 + fq) ^ (row & 7);
            af[mt][kk] = *(const bf16x8*)(&Abuf[row * KHALF + g * 8]);
        }
    #pragma unroll
    for (int mt = 0; mt < 2; ++mt)
        #pragma unroll
        for (int kk = 0; kk < 4; ++kk)
            asm volatile("" : "+v"(af[mt][kk]));

    // ---- B pipeline: raw x2 global -> fp32 regs (1 chunk ahead) -> bf16 frags ----
    float4 bnx[2][4][2];   // [nt][kk][half] fp32 in flight
    bf16x8 bcur[4][2];     // [kk][nt] current bf16 fragments

    auto loadB = [&](int cn) {
        const bool safe = ((cn + 1) * NCHUNK <= WW);   // tail chunk needs masking
        #pragma unroll
        for (int nt = 0; nt < 2; ++nt) {
            const int row = cn * NCHUNK + nt * 16 + fr;
            const float* s = x2b + (size_t)row * CCH + fq * 8;
            if (safe || row < WW) {
                #pragma unroll
                for (int kk = 0; kk < 4; ++kk) {
                    bnx[nt][kk][0] = *(const float4*)(s + kk * 32);
                    bnx[nt][kk][1] = *(const float4*)(s + kk * 32 + 4);
                }
            } else {
                #pragma unroll
                for (int kk = 0; kk < 4; ++kk) {
                    bnx[nt][kk][0] = make_float4(0.f, 0.f, 0.f, 0.f);
                    bnx[nt][kk][1] = make_float4(0.f, 0.f, 0.f, 0.f);
                }
            }
        }
    };
    auto cvtB = [&]() {
        #pragma unroll
        for (int kk = 0; kk < 4; ++kk)
            #pragma unroll
            for (int nt = 0; nt < 2; ++nt) {
                float4 a = bnx[nt][kk][0], c = bnx[nt][kk][1];
                bf16x8 v;
                v[0] = (__bf16)a.x; v[1] = (__bf16)a.y; v[2] = (__bf16)a.z; v[3] = (__bf16)a.w;
                v[4] = (__bf16)c.x; v[5] = (__bf16)c.y; v[6] = (__bf16)c.z; v[7] = (__bf16)c.w;
                bcur[kk][nt] = v;
            }
    };

    loadB(0);
    cvtB();

    for (int chunk = 0; chunk < NCHUNKS; ++chunk) {
        if (chunk + 1 < NCHUNKS) loadB(chunk + 1);   // issue next chunk's loads early

        f32x4 acc[2][2];
        #pragma unroll
        for (int mt = 0; mt < 2; ++mt)
            #pragma unroll
            for (int nt = 0; nt < 2; ++nt)
                acc[mt][nt] = (f32x4){0.f, 0.f, 0.f, 0.f};

        #pragma unroll
        for (int kk = 0; kk < 4; ++kk)
            #pragma unroll
            for (int mt = 0; mt < 2; ++mt)
                #pragma unroll
                for (int nt = 0; nt < 2; ++nt)
                    acc[mt][nt] = __builtin_amdgcn_mfma_f32_16x16x32_bf16(
                        af[mt][kk], bcur[kk][nt], acc[mt][nt], 0, 0, 0);

        // ---- epilogue (proven since R6): combine equal tile-diagonals, scatter ----
        {
            f32x4 c0 = acc[0][1];                    // dd = 0
            f32x4 c1 = acc[0][0] + acc[1][1];        // dd = 1
            f32x4 c2 = acc[1][0];                    // dd = 2
            const int mub = 4 * fq;
            #pragma unroll
            for (int r = 0; r < 4; ++r) {
                const int mu = mub + r;
                const int dr = mu - fr + 15;         // 0..30
                scratch[wave][mu][dr]      = c0[r];
                scratch[wave][mu][dr + 16] = c1[r];
                scratch[wave][mu][dr + 32] = c2[r];
            }
        }
        // wave-coherent rowsum + atomic into block partial (no barrier needed)
        {
            float s = 0.f;
            #pragma unroll
            for (int m = 0; m < 16; ++m) s += scratch[wave][m][lane];
            if (lane < 63) {
                int v = m0 + 32 * wave - 32 * chunk + lane + 1319;  // in [423, 2373]
                if (v >= 1800) v -= 900;
                if (v >= 900) v -= 900;
                unsafeAtomicAdd(&partial[v], s);
            }
        }

        if (chunk + 1 < NCHUNKS) cvtB();   // vmcnt wait lands here, under MFMA+epilogue
    }

    __syncthreads();
    for (int i = tid; i < WW; i += 256)
        unsafeAtomicAdd(&out[(size_t)b * WW + i], partial[i]);  // 16 blocks per batch
}

extern "C" void kernel_launch(void* const* d_in, const int* in_sizes, int n_in,
                              void* d_out, int out_size, void* d_ws, size_t ws_size,
                              hipStream_t stream) {
    const float* x1 = (const float*)d_in[0];
    const float* x2 = (const float*)d_in[1];
    float* out = (float*)d_out;
    float* ws = (float*)d_ws;

    const size_t need15 = (size_t)(SUMS_OFF + 15 * 64 * 256) * sizeof(float);  // ~1.05 MB
    const int segs = (ws_size >= need15) ? 15 : 4;
    const int rowsper = (WW + segs - 1) / segs;

    hipMemsetAsync(d_out, 0, (size_t)out_size * sizeof(float), stream);
    nc_norm_partial<<<2 * 32 * segs, 256, 0, stream>>>(x1, x2, ws + SUMS_OFF, segs, rowsper);
    nc_norm_finalize<<<32, 256, 0, stream>>>(ws, segs);
    nc_corr<<<512, 256, 0, stream>>>(x1, x2, ws, out);
}

// Round 9
// 75.336 us; speedup vs baseline: 1.7494x; 1.7494x over previous
//
#include <hip/hip_runtime.h>
#include <hip/hip_bf16.h>

#define BATCH 32
#define WW 900
#define CCH 256
#define KHALF 128     // K columns per block (K-split x2)
#define MSTRIP 128    // M rows per block
#define NCHUNK 32     // B rows staged per chunk
#define NCHUNKS 30    // 30*32 = 960 >= 900 (even -> chunk pairs)

typedef __bf16 bf16x8 __attribute__((ext_vector_type(8)));
typedef __bf16 bf16x4 __attribute__((ext_vector_type(4)));
typedef float f32x4 __attribute__((ext_vector_type(4)));

// ws layout (floats): sums[2*32*segs*256] at offset 0
// ---------------- norm pass 1: partial sums of squares ----------------
__global__ void nc_norm_partial(const float* __restrict__ x1,
                                const float* __restrict__ x2,
                                float* __restrict__ sums,
                                int segs, int rowsper) {
    int blk = blockIdx.x;
    int seg = blk % segs;
    int b = (blk / segs) & 31;
    int which = blk / (segs * 32);
    const float* x = which ? x2 : x1;
    int c = threadIdx.x;
    int r0 = seg * rowsper;
    int r1 = r0 + rowsper;
    if (r1 > WW) r1 = WW;
    const float* p = x + ((size_t)b * WW + r0) * CCH + c;
    float s = 0.f;
    #pragma unroll 4
    for (int w = 0; w < r1 - r0; ++w) {
        float v = p[(size_t)w * CCH];
        s = fmaf(v, v, s);
    }
    sums[(((size_t)(which * 32 + b)) * segs + seg) * CCH + c] = s;
}

// ---------------- main: GEMM + diagonal reduction (R6 skeleton, slim epilogue) ----------------
// grid = 512: b = blockIdx&31 (XCD-local per batch), strip = (blockIdx>>5)&7, kh = blockIdx>>8.
// A' = x1*inv1*inv2 staged once in LDS (bf16, swizzled); B = raw x2, double-buffered,
// coalesced stage, 1 barrier/chunk. Epilogue: stride-19 [dr][mu] scratch (write2/read2
// friendly), per-wave rowsum -> diag -> ownership fold. A frags read once per chunk-PAIR.
__global__ __launch_bounds__(256, 2)
void nc_corr(const float* __restrict__ x1,
             const float* __restrict__ x2,
             const float* __restrict__ sums,
             float* __restrict__ out,
             int segs) {
    __shared__ __bf16 Abuf[MSTRIP * KHALF];       // 32 KB
    __shared__ __bf16 Bbuf[2][NCHUNK * KHALF];    // 2 x 8 KB
    __shared__ float scratch[4][63][19];          // 18.7 KB, stride 19 (odd -> 2-way banks)
    __shared__ float diag[2][4][64];              // 2 KB
    __shared__ float partial[WW];                 // 3.6 KB
    __shared__ float invbuf[KHALF];               // 0.5 KB

    const int tid = threadIdx.x;
    const int b = blockIdx.x & 31;
    const int strip = (blockIdx.x >> 5) & 7;
    const int kh = blockIdx.x >> 8;
    const int m0 = strip * MSTRIP;
    const int k0 = kh * KHALF;

    const float* __restrict__ x1b = x1 + (size_t)b * WW * CCH + k0;
    const float* __restrict__ x2b = x2 + (size_t)b * WW * CCH + k0;

    const int lane = tid & 63;
    const int wave = tid >> 6;     // m-slice: rows m0 + wave*32 .. +31
    const int fr = lane & 15;
    const int fq = lane >> 4;
    const int sr = tid >> 5;       // staging row base 0..7
    const int sg = tid & 31;       // staging float4 col 0..31

    // ---- B staging (raw x2: no normalization needed) ----
    float4 st[4];
    auto loadB = [&](int chunk) {
        #pragma unroll
        for (int k = 0; k < 4; ++k) {
            const int row = chunk * NCHUNK + sr + 8 * k;
            st[k] = (row < WW) ? *(const float4*)(x2b + (size_t)row * CCH + sg * 4)
                               : make_float4(0.f, 0.f, 0.f, 0.f);
        }
    };
    auto writeB = [&](int buf) {
        #pragma unroll
        for (int k = 0; k < 4; ++k) {
            const int row = sr + 8 * k;        // 0..31
            float4 f = st[k];
            bf16x4 v = { (__bf16)f.x, (__bf16)f.y, (__bf16)f.z, (__bf16)f.w };
            *(bf16x4*)(&Bbuf[buf][row * KHALF + (((sg >> 1) ^ (row & 7)) << 3) + (sg & 1) * 4]) = v;
        }
    };

    loadB(0);

    // ---- zero partial/scratch; fused finalize: inv12 = rsqrt(s1)*rsqrt(s2) ----
    for (int i = tid; i < WW; i += 256) partial[i] = 0.f;
    for (int i = tid; i < 4 * 63 * 19; i += 256) ((float*)scratch)[i] = 0.f;
    if (tid < KHALF) {
        const int c = k0 + tid;
        float t1 = 0.f, t2 = 0.f;
        for (int q = 0; q < segs; ++q) {
            t1 += sums[((size_t)(b * segs + q)) * CCH + c];
            t2 += sums[((size_t)((32 + b) * segs + q)) * CCH + c];
        }
        invbuf[tid] = rsqrtf(fmaxf(t1, 1e-12f)) * rsqrtf(fmaxf(t2, 1e-12f));
    }
    writeB(0);
    __syncthreads();   // invbuf ready

    // ---- Stage A' once: x1 * inv12, coalesced, bf16, swizzled ----
    {
        float4 iv = *(const float4*)(&invbuf[sg * 4]);
        #pragma unroll
        for (int k = 0; k < 16; ++k) {
            const int row = sr + 8 * k;        // 0..127
            const int m = m0 + row;
            float4 f = make_float4(0.f, 0.f, 0.f, 0.f);
            if (m < WW) f = *(const float4*)(x1b + (size_t)m * CCH + sg * 4);
            bf16x4 v = { (__bf16)(f.x * iv.x), (__bf16)(f.y * iv.y),
                         (__bf16)(f.z * iv.z), (__bf16)(f.w * iv.w) };
            *(bf16x4*)(&Abuf[row * KHALF + (((sg >> 1) ^ (row & 7)) << 3) + (sg & 1) * 4]) = v;
        }
    }
    __syncthreads();   // Abuf + Bbuf[0] ready; zeros done

    int cur = 0;
    for (int pair = 0; pair < NCHUNKS / 2; ++pair) {
        // ---- A fragments once per pair (worst case compiler re-reads = R6 cost) ----
        bf16x8 af[2][4];
        #pragma unroll
        for (int mt = 0; mt < 2; ++mt)
            #pragma unroll
            for (int kk = 0; kk < 4; ++kk) {
                const int row = wave * 32 + mt * 16 + fr;
                const int g = (kk * 4 + fq) ^ (row & 7);
                af[mt][kk] = *(const bf16x8*)(&Abuf[row * KHALF + g * 8]);
            }

        #pragma unroll
        for (int sub = 0; sub < 2; ++sub) {
            const int chunk = 2 * pair + sub;
            if (chunk + 1 < NCHUNKS) loadB(chunk + 1);   // issue early (T14)

            f32x4 acc[2][2];
            #pragma unroll
            for (int mt = 0; mt < 2; ++mt)
                #pragma unroll
                for (int nt = 0; nt < 2; ++nt)
                    acc[mt][nt] = (f32x4){0.f, 0.f, 0.f, 0.f};

            #pragma unroll
            for (int kk = 0; kk < 4; ++kk) {
                bf16x8 bfr[2];
                #pragma unroll
                for (int nt = 0; nt < 2; ++nt) {
                    const int row = nt * 16 + fr;
                    const int g = (kk * 4 + fq) ^ (row & 7);
                    bfr[nt] = *(const bf16x8*)(&Bbuf[cur][row * KHALF + g * 8]);
                }
                #pragma unroll
                for (int mt = 0; mt < 2; ++mt)
                    #pragma unroll
                    for (int nt = 0; nt < 2; ++nt)
                        acc[mt][nt] = __builtin_amdgcn_mfma_f32_16x16x32_bf16(
                            af[mt][kk], bfr[nt], acc[mt][nt], 0, 0, 0);
            }

            // ---- scatter: [dr][mu] layout; adjacent-r stores merge to ds_write2_b32 ----
            {
                f32x4 c0 = acc[0][1];                    // dd = 0
                f32x4 c1 = acc[0][0] + acc[1][1];        // dd = 1
                f32x4 c2 = acc[1][0];                    // dd = 2
                const int mu0 = 4 * fq;
                const int drb = mu0 - fr + 15;           // dr for r=0 (0..30)
                #pragma unroll
                for (int r = 0; r < 4; ++r) {
                    scratch[wave][drb + r][mu0 + r]      = c0[r];
                    scratch[wave][drb + r + 16][mu0 + r] = c1[r];
                    scratch[wave][drb + r + 32][mu0 + r] = c2[r];
                }
            }
            // ---- rowsum: 16 adjacent dwords -> ds_read2_b32 x8 ----
            if (lane < 63) {
                float s = 0.f;
                #pragma unroll
                for (int m = 0; m < 16; ++m) s += scratch[wave][lane][m];
                diag[chunk & 1][wave][lane] = s;
            }

            if (chunk + 1 < NCHUNKS) writeB(cur ^ 1);
            __syncthreads();

            // ---- ownership fold: unique j per tid -> plain LDS RMW ----
            if (tid < 159) {
                float s = 0.f;
                #pragma unroll
                for (int w = 0; w < 4; ++w) {
                    const int dr = tid - 32 * w;
                    if (dr >= 0 && dr < 63) s += diag[chunk & 1][w][dr];
                }
                int v = m0 - 32 * chunk + tid + 1319;    // in [391, 2245]
                if (v >= 1800) v -= 900;
                if (v >= 900) v -= 900;
                partial[v] += s;
            }
            cur ^= 1;
        }
    }

    __syncthreads();
    for (int i = tid; i < WW; i += 256)
        unsafeAtomicAdd(&out[(size_t)b * WW + i], partial[i]);  // 16 blocks per batch
}

extern "C" void kernel_launch(void* const* d_in, const int* in_sizes, int n_in,
                              void* d_out, int out_size, void* d_ws, size_t ws_size,
                              hipStream_t stream) {
    const float* x1 = (const float*)d_in[0];
    const float* x2 = (const float*)d_in[1];
    float* out = (float*)d_out;
    float* ws = (float*)d_ws;

    const size_t need15 = (size_t)2 * 32 * 15 * 256 * sizeof(float);  // 983 KB
    const int segs = (ws_size >= need15) ? 15 : 4;
    const int rowsper = (WW + segs - 1) / segs;

    hipMemsetAsync(d_out, 0, (size_t)out_size * sizeof(float), stream);
    nc_norm_partial<<<2 * 32 * segs, 256, 0, stream>>>(x1, x2, ws, segs, rowsper);
    nc_corr<<<512, 256, 0, stream>>>(x1, x2, ws, out, segs);
}